// Round 20
// baseline (245.253 us; speedup 1.0000x reference)
//
#include <hip/hip_runtime.h>
#include <hip/hip_bf16.h>

typedef signed char i8_t;
typedef int i32x4 __attribute__((ext_vector_type(4)));
typedef float f32x4 __attribute__((ext_vector_type(4)));
typedef unsigned short u16x8 __attribute__((ext_vector_type(8)));

typedef const __attribute__((address_space(1))) void* gptr_t;
typedef __attribute__((address_space(3))) void* sptr_t;

#define GLD16(g, l) __builtin_amdgcn_global_load_lds((gptr_t)(g), (sptr_t)(l), 16, 0, 0)

// ---------------------------------------------------------------------------
// Kernel 1: global sum of W (fp32 partials, double atomic) -> ws scalar
// ---------------------------------------------------------------------------
__global__ void sum_w_kernel(const float* __restrict__ W, double* __restrict__ out, int n4) {
    int i = blockIdx.x * blockDim.x + threadIdx.x;
    int stride = gridDim.x * blockDim.x;
    float s = 0.f;
    for (; i < n4; i += stride) {
        float4 v = ((const float4*)W)[i];
        s += (v.x + v.y) + (v.z + v.w);
    }
    #pragma unroll
    for (int off = 32; off > 0; off >>= 1) s += __shfl_down(s, off, 64);
    __shared__ float red[4];
    int t = threadIdx.x;
    if ((t & 63) == 0) red[t >> 6] = s;
    __syncthreads();
    if (t == 0) {
        float bs = red[0] + red[1] + red[2] + red[3];
        atomicAdd(out, (double)bs);
    }
}

// ---------------------------------------------------------------------------
// Kernel 2: quantize W -> i8 {0,1}
// ---------------------------------------------------------------------------
__global__ void quant_w_kernel(const float* __restrict__ W, i8_t* __restrict__ Wq,
                               const double* __restrict__ sumw, float inv_n, int n4) {
    float mean = (float)(*sumw) * inv_n;
    int i = blockIdx.x * blockDim.x + threadIdx.x;
    int stride = gridDim.x * blockDim.x;
    for (; i < n4; i += stride) {
        float4 v = ((const float4*)W)[i];
        char4 o;
        o.x = (v.x > mean) ? 1 : 0;
        o.y = (v.y > mean) ? 1 : 0;
        o.z = (v.z > mean) ? 1 : 0;
        o.w = (v.w > mean) ? 1 : 0;
        ((char4*)Wq)[i] = o;
    }
}

// ---------------------------------------------------------------------------
// Kernel 3: per-row symmetric int8 quantization of x (one block per row).
// ---------------------------------------------------------------------------
__global__ void quant_x_kernel(const float* __restrict__ x, i8_t* __restrict__ xq,
                               float* __restrict__ scale, int K) {
    __shared__ float red[4];
    int row = blockIdx.x;
    int t = threadIdx.x;
    const float4* xr = (const float4*)(x + (size_t)row * K);

    float4 v[4];
    float am = 0.f;
    #pragma unroll
    for (int j = 0; j < 4; ++j) {
        v[j] = xr[t + j * 256];
        am = fmaxf(am, fmaxf(fmaxf(fabsf(v[j].x), fabsf(v[j].y)),
                             fmaxf(fabsf(v[j].z), fabsf(v[j].w))));
    }
    #pragma unroll
    for (int off = 32; off > 0; off >>= 1) am = fmaxf(am, __shfl_down(am, off, 64));
    if ((t & 63) == 0) red[t >> 6] = am;
    __syncthreads();
    float amax = fmaxf(fmaxf(red[0], red[1]), fmaxf(red[2], red[3]));
    amax = fmaxf(amax, 1e-20f);
    float s = amax * (1.0f / 127.0f);
    float inv = 127.0f / amax;
    if (t == 0) scale[row] = s;

    char4* oq = (char4*)(xq + (size_t)row * K);
    #pragma unroll
    for (int j = 0; j < 4; ++j) {
        char4 o;
        o.x = (i8_t)(int)rintf(fminf(fmaxf(v[j].x * inv, -127.f), 127.f));
        o.y = (i8_t)(int)rintf(fminf(fmaxf(v[j].y * inv, -127.f), 127.f));
        o.z = (i8_t)(int)rintf(fminf(fmaxf(v[j].z * inv, -127.f), 127.f));
        o.w = (i8_t)(int)rintf(fminf(fmaxf(v[j].w * inv, -127.f), 127.f));
        oq[t + j * 256] = o;
    }
}

// ---------------------------------------------------------------------------
// Kernel 4: quantize b (single block; n = 4096)
// ---------------------------------------------------------------------------
__global__ void quant_b_kernel(const float* __restrict__ b, float* __restrict__ bq, int n) {
    int t = threadIdx.x;
    float s = 0.f;
    for (int i = t; i < n; i += 256) s += b[i];
    #pragma unroll
    for (int off = 32; off > 0; off >>= 1) s += __shfl_down(s, off, 64);
    __shared__ float red[4];
    if ((t & 63) == 0) red[t >> 6] = s;
    __syncthreads();
    float mean = (red[0] + red[1] + red[2] + red[3]) / (float)n;
    for (int i = t; i < n; i += 256) bq[i] = (b[i] > mean) ? 1.0f : 0.0f;
}

// ---------------------------------------------------------------------------
// Kernel 5: INT8 MFMA GEMM, 256x256 tile, BK=128, 8 waves (2Mx4N), R12's
// proven 4-phase schedule (best verified). bf16-z epilogue (ZMODE=1) halves
// C-write + rownorm-read bytes; fp32 fallback if ws too small.
// ---------------------------------------------------------------------------
#define PRIO1 __builtin_amdgcn_s_setprio(1)
#define PRIO0 __builtin_amdgcn_s_setprio(0)
#define BAR() __builtin_amdgcn_s_barrier()
#define WAITV4() asm volatile("s_waitcnt vmcnt(4)" ::: "memory")
#define WAITV0() asm volatile("s_waitcnt vmcnt(0)" ::: "memory")
#define UNRL _Pragma("unroll")

__device__ __forceinline__ unsigned short f2bfu(float f) {
    __hip_bfloat16 h = __float2bfloat16(f);
    return *(unsigned short*)&h;
}

template<int ZMODE>
__global__ __launch_bounds__(512, 2) void gemm_i8_256(
        const i8_t* __restrict__ A, const i8_t* __restrict__ B,
        float* __restrict__ C, unsigned short* __restrict__ ZB,
        int M, int N, int K) {
    __shared__ int lds32[32768];       // 128 KiB: [buf][A 32K i8 | B 32K i8]
    char* ldsc = (char*)lds32;
    float* ldsf = (float*)lds32;       // epilogue bounce reuses the same LDS

    int nbn = N >> 8;
    int nwg = gridDim.x;
    int bid = blockIdx.x;
    int cpx = nwg >> 3;
    int wg = (bid & 7) * cpx + (bid >> 3);   // XCD swizzle (nwg % 8 == 0)
    int tm = wg / nbn, tn = wg % nbn;

    int t = threadIdx.x;
    int w = t >> 6, l = t & 63;
    int wr = w >> 2, wc = w & 3;             // 2 M-waves x 4 N-waves
    int wrOff = wr * 8192;                   // 64 rows * 128 B
    int wcOff = wc * 4096;                   // 32 rows * 128 B

    // read-side lane offsets (bytes), full-granule swizzle folded in
    int baseL = ((l & 15) * 128) + ((l >> 4) * 16);
    int laneA0 = baseL ^ ((l & 7) << 4);     // K bytes 0..63
    int laneA1 = laneA0 ^ 64;                // K bytes 64..127

    // stage-side source offsets (i8 elems == bytes), inverse swizzle
    int offA[2][2], offB[2][2];
    UNRL
    for (int c = 0; c < 2; ++c) {
        int o = (t + c * 512) * 16;
        int os = o ^ ((o >> 3) & 0x70);
        int lr = os >> 7;
        int col = os & 127;
        UNRL
        for (int h = 0; h < 2; ++h) {
            offA[c][h] = ((lr >> 6) * 128 + h * 64 + (lr & 63)) * K + col;
            offB[c][h] = ((lr >> 5) * 64 + h * 32 + (lr & 31)) * K + col;
        }
    }

    const i8_t* srcA = A + (size_t)tm * 256 * K;
    const i8_t* srcB = B + (size_t)tn * 256 * K;

    i32x4 acc[8][4] = {};
    i32x4 af[4][2], bf0[2][2], bf1[2][2];

#define STAGE_A(P, H, KIDX) do { \
    GLD16(srcA + (size_t)offA[0][H] + (KIDX), ldsc + (P)*65536 + (H)*16384 + w*1024); \
    GLD16(srcA + (size_t)offA[1][H] + (KIDX), ldsc + (P)*65536 + (H)*16384 + 8192 + w*1024); \
} while (0)
#define STAGE_B(P, H, KIDX) do { \
    GLD16(srcB + (size_t)offB[0][H] + (KIDX), ldsc + (P)*65536 + 32768 + (H)*16384 + w*1024); \
    GLD16(srcB + (size_t)offB[1][H] + (KIDX), ldsc + (P)*65536 + 32768 + (H)*16384 + 8192 + w*1024); \
} while (0)
#define LOAD_AF(P, H) do { UNRL for (int f = 0; f < 4; ++f) { \
    af[f][0] = *(const i32x4*)(ldsc + (P)*65536 + (H)*16384 + wrOff + f*2048 + laneA0); \
    af[f][1] = *(const i32x4*)(ldsc + (P)*65536 + (H)*16384 + wrOff + f*2048 + laneA1); \
} } while (0)
#define LOAD_BF(BF, P, H) do { UNRL for (int e = 0; e < 2; ++e) { \
    BF[e][0] = *(const i32x4*)(ldsc + (P)*65536 + 32768 + (H)*16384 + wcOff + e*2048 + laneA0); \
    BF[e][1] = *(const i32x4*)(ldsc + (P)*65536 + 32768 + (H)*16384 + wcOff + e*2048 + laneA1); \
} } while (0)
#define MFMA_Q(QM, QN, BF) do { UNRL for (int f = 0; f < 4; ++f) UNRL for (int e = 0; e < 2; ++e) { \
    acc[(QM)*4+f][(QN)*2+e] = __builtin_amdgcn_mfma_i32_16x16x64_i8(af[f][0], BF[e][0], acc[(QM)*4+f][(QN)*2+e], 0, 0, 0); \
    acc[(QM)*4+f][(QN)*2+e] = __builtin_amdgcn_mfma_i32_16x16x64_i8(af[f][1], BF[e][1], acc[(QM)*4+f][(QN)*2+e], 0, 0, 0); \
} } while (0)

#define TILE(P, PN, KTN) do { \
    LOAD_AF(P, 0); LOAD_BF(bf0, P, 0); STAGE_A(PN, 0, KTN); \
    PRIO1; MFMA_Q(0, 0, bf0); PRIO0; WAITV4(); BAR(); \
    LOAD_BF(bf1, P, 1);                STAGE_B(PN, 0, KTN); \
    PRIO1; MFMA_Q(0, 1, bf1); PRIO0; WAITV4(); BAR(); \
    LOAD_AF(P, 1);                     STAGE_B(PN, 1, KTN); \
    PRIO1; MFMA_Q(1, 1, bf1); PRIO0; WAITV4(); BAR(); \
                                       STAGE_A(PN, 1, KTN); \
    PRIO1; MFMA_Q(1, 0, bf0); PRIO0; WAITV4(); BAR(); \
} while (0)

    // prologue: stage tile 0 (K 0..127) into buf0, drain once
    STAGE_A(0, 0, 0); STAGE_B(0, 0, 0); STAGE_B(0, 1, 0); STAGE_A(0, 1, 0);
    WAITV0();
    BAR();

    for (int kt = 0; kt < K; kt += 256) {
        int kn1 = kt + 128;
        int kn2 = (kt + 256 < K) ? kt + 256 : 0;   // wrap: redundant, never read
        TILE(0, 1, kn1);
        TILE(1, 0, kn2);
    }

    WAITV0();  // drain trailing stages (incl. wrapped GLD16 into the buffers)
    BAR();     // all waves' LDS writes retired before bounce reuse

    // Coalesced epilogue via LDS bounce. Frag layout: (fm,fn,r) at
    // row = wr*128 + fm*16 + (l>>4)*4 + r, col = wc*64 + fn*16 + (l&15).
    {
        int crowW = tm * 256 + wr * 128;
        int ccolW = tn * 256 + wc * 64;
        int lq = l >> 4, lc = l & 15;
        UNRL
        for (int c = 0; c < 4; ++c) {
            UNRL
            for (int fi = 0; fi < 2; ++fi) {
                int fm = c * 2 + fi;
                UNRL
                for (int fn = 0; fn < 4; ++fn)
                    UNRL
                    for (int r = 0; r < 4; ++r)
                        ldsf[w * 2176 + (fi * 16 + lq * 4 + r) * 68 + fn * 16 + lc]
                            = (float)acc[fm][fn][r];
            }
            BAR();
            UNRL
            for (int rr = 0; rr < 8; ++rr) {
                f32x4 v = *(const f32x4*)&ldsf[w * 2176 + (rr * 4 + lq) * 68 + lc * 4];
                size_t row = (size_t)(crowW + c * 32 + rr * 4 + lq);
                if (ZMODE == 0) {
                    *(f32x4*)&C[row * N + (ccolW + lc * 4)] = v;
                } else {
                    ushort4 h;
                    h.x = f2bfu(v[0]); h.y = f2bfu(v[1]);
                    h.z = f2bfu(v[2]); h.w = f2bfu(v[3]);
                    *(ushort4*)&ZB[row * N + (ccolW + lc * 4)] = h;
                }
            }
            BAR();
        }
    }
}

// ---------------------------------------------------------------------------
// Kernel 6a (fp32-z fallback): in-place rownorm on d_out.
// ---------------------------------------------------------------------------
__device__ __forceinline__ float block_sum_256(float v, float* red) {
    #pragma unroll
    for (int off = 32; off > 0; off >>= 1) v += __shfl_down(v, off, 64);
    int t = threadIdx.x;
    __syncthreads();
    if ((t & 63) == 0) red[t >> 6] = v;
    __syncthreads();
    return red[0] + red[1] + red[2] + red[3];
}

__global__ void rownorm_kernel(float* __restrict__ z, const float* __restrict__ bq,
                               const float* __restrict__ scale, int N) {
    __shared__ float red[4];
    int row = blockIdx.x;
    float* zr = z + (size_t)row * N;
    float srow = scale[row];
    int t = threadIdx.x;

    float4 v[4];
    float s = 0.f;
    #pragma unroll
    for (int j = 0; j < 4; ++j) {
        int idx = t + j * 256;
        float4 a = ((const float4*)zr)[idx];
        float4 bb = ((const float4*)bq)[idx];
        a.x = a.x * srow + bb.x; a.y = a.y * srow + bb.y;
        a.z = a.z * srow + bb.z; a.w = a.w * srow + bb.w;
        v[j] = a;
        s += (a.x + a.y) + (a.z + a.w);
    }
    float total = block_sum_256(s, red);
    float mean = total * (1.0f / 4096.0f);

    float q = 0.f;
    #pragma unroll
    for (int j = 0; j < 4; ++j) {
        float dx = v[j].x - mean, dy = v[j].y - mean, dz = v[j].z - mean, dw = v[j].w - mean;
        q += (dx * dx + dy * dy) + (dz * dz + dw * dw);
    }
    float qtot = block_sum_256(q, red);
    float var = qtot * (1.0f / 4095.0f);
    float inv = 1.0f / (sqrtf(var) + 1e-8f);

    #pragma unroll
    for (int j = 0; j < 4; ++j) {
        int idx = t + j * 256;
        float4 o;
        o.x = (v[j].x - mean) * inv;
        o.y = (v[j].y - mean) * inv;
        o.z = (v[j].z - mean) * inv;
        o.w = (v[j].w - mean) * inv;
        ((float4*)zr)[idx] = o;
    }
}

// ---------------------------------------------------------------------------
// Kernel 6b (bf16-z path): read bf16 z from ws, write fp32 out.
// R20: `out` stores are NONTEMPORAL (never re-read; avoids L2/L3
// write-allocate evicting the L3-resident zb being streamed in).
// ---------------------------------------------------------------------------
__global__ void rownorm_bf16_kernel(const unsigned short* __restrict__ zb,
                                    float* __restrict__ out,
                                    const float* __restrict__ bq,
                                    const float* __restrict__ scale, int N) {
    __shared__ float red[4];
    int row = blockIdx.x;
    const unsigned short* zr = zb + (size_t)row * N;
    float* orow = out + (size_t)row * N;
    float srow = scale[row];
    int t = threadIdx.x;

    float v[16];
    float s = 0.f;
    #pragma unroll
    for (int j = 0; j < 2; ++j) {
        int idx8 = t + j * 256;                 // ushort8 index
        u16x8 u = ((const u16x8*)zr)[idx8];
        float4 b0 = ((const float4*)bq)[idx8 * 2];
        float4 b1 = ((const float4*)bq)[idx8 * 2 + 1];
        #pragma unroll
        for (int e = 0; e < 8; ++e) {
            unsigned int bits = ((unsigned int)u[e]) << 16;
            float f = *(float*)&bits;
            float bb = (e < 4) ? ((const float*)&b0)[e] : ((const float*)&b1)[e - 4];
            float a = f * srow + bb;
            v[j * 8 + e] = a;
            s += a;
        }
    }
    float total = block_sum_256(s, red);
    float mean = total * (1.0f / 4096.0f);

    float q = 0.f;
    #pragma unroll
    for (int i = 0; i < 16; ++i) {
        float d = v[i] - mean;
        q += d * d;
    }
    float qtot = block_sum_256(q, red);
    float var = qtot * (1.0f / 4095.0f);
    float inv = 1.0f / (sqrtf(var) + 1e-8f);

    #pragma unroll
    for (int j = 0; j < 2; ++j) {
        int idx8 = t + j * 256;
        #pragma unroll
        for (int p = 0; p < 2; ++p) {
            f32x4 o;
            o[0] = (v[j * 8 + p * 4 + 0] - mean) * inv;
            o[1] = (v[j * 8 + p * 4 + 1] - mean) * inv;
            o[2] = (v[j * 8 + p * 4 + 2] - mean) * inv;
            o[3] = (v[j * 8 + p * 4 + 3] - mean) * inv;
            __builtin_nontemporal_store(o, (f32x4*)&orow[(idx8 * 2 + p) * 4]);
        }
    }
}

// ---------------------------------------------------------------------------
extern "C" void kernel_launch(void* const* d_in, const int* in_sizes, int n_in,
                              void* d_out, int out_size, void* d_ws, size_t ws_size,
                              hipStream_t stream) {
    const float* x = (const float*)d_in[0];
    const float* W = (const float*)d_in[1];
    const float* b = (const float*)d_in[2];
    float* out = (float*)d_out;

    const int N = in_sizes[2];            // 4096 (OUT)
    const int K = in_sizes[1] / N;        // 4096 (IN)
    const int M = in_sizes[0] / K;        // 8192

    // workspace layout
    char* ws = (char*)d_ws;
    size_t off_xq = 0;
    size_t off_wq = off_xq + (size_t)M * K;                 // i8
    size_t off_scales = off_wq + (size_t)N * K;             // i8
    size_t off_bq = off_scales + (size_t)M * 4;
    size_t off_sumw = off_bq + (size_t)N * 4;
    size_t off_zb = (off_sumw + 8 + 15) & ~(size_t)15;      // 16-aligned
    size_t need_bf16z = off_zb + (size_t)M * N * 2;

    i8_t* xq = (i8_t*)(ws + off_xq);
    i8_t* wq = (i8_t*)(ws + off_wq);
    float* scales = (float*)(ws + off_scales);
    float* bq = (float*)(ws + off_bq);
    double* sumw = (double*)(ws + off_sumw);
    unsigned short* zb = (unsigned short*)(ws + off_zb);

    bool use_bf16z = (ws_size >= need_bf16z);

    hipMemsetAsync(sumw, 0, sizeof(double), stream);
    sum_w_kernel<<<2048, 256, 0, stream>>>(W, sumw, N * K / 4);
    quant_w_kernel<<<2048, 256, 0, stream>>>(W, wq, sumw, 1.0f / (float)((size_t)N * K), N * K / 4);
    quant_x_kernel<<<M, 256, 0, stream>>>(x, xq, scales, K);
    quant_b_kernel<<<1, 256, 0, stream>>>(b, bq, N);

    int grid = (M / 256) * (N / 256);
    if (use_bf16z) {
        gemm_i8_256<1><<<grid, 512, 0, stream>>>(xq, wq, out, zb, M, N, K);
        rownorm_bf16_kernel<<<M, 256, 0, stream>>>(zb, out, bq, scales, N);
    } else {
        gemm_i8_256<0><<<grid, 512, 0, stream>>>(xq, wq, out, zb, M, N, K);
        rownorm_kernel<<<M, 256, 0, stream>>>(out, bq, scales, N);
    }
}

// Round 21
// 228.231 us; speedup vs baseline: 1.0746x; 1.0746x over previous
//
#include <hip/hip_runtime.h>
#include <hip/hip_bf16.h>

typedef signed char i8_t;
typedef int i32x4 __attribute__((ext_vector_type(4)));
typedef float f32x4 __attribute__((ext_vector_type(4)));
typedef unsigned short u16x8 __attribute__((ext_vector_type(8)));

typedef const __attribute__((address_space(1))) void* gptr_t;
typedef __attribute__((address_space(3))) void* sptr_t;

#define GLD16(g, l) __builtin_amdgcn_global_load_lds((gptr_t)(g), (sptr_t)(l), 16, 0, 0)

// ---------------------------------------------------------------------------
// Kernel 1: global sum of W (fp32 partials, double atomic) -> ws scalar
// ---------------------------------------------------------------------------
__global__ void sum_w_kernel(const float* __restrict__ W, double* __restrict__ out, int n4) {
    int i = blockIdx.x * blockDim.x + threadIdx.x;
    int stride = gridDim.x * blockDim.x;
    float s = 0.f;
    for (; i < n4; i += stride) {
        float4 v = ((const float4*)W)[i];
        s += (v.x + v.y) + (v.z + v.w);
    }
    #pragma unroll
    for (int off = 32; off > 0; off >>= 1) s += __shfl_down(s, off, 64);
    __shared__ float red[4];
    int t = threadIdx.x;
    if ((t & 63) == 0) red[t >> 6] = s;
    __syncthreads();
    if (t == 0) {
        float bs = red[0] + red[1] + red[2] + red[3];
        atomicAdd(out, (double)bs);
    }
}

// ---------------------------------------------------------------------------
// Kernel 2: quantize W -> i8 {0,1}
// ---------------------------------------------------------------------------
__global__ void quant_w_kernel(const float* __restrict__ W, i8_t* __restrict__ Wq,
                               const double* __restrict__ sumw, float inv_n, int n4) {
    float mean = (float)(*sumw) * inv_n;
    int i = blockIdx.x * blockDim.x + threadIdx.x;
    int stride = gridDim.x * blockDim.x;
    for (; i < n4; i += stride) {
        float4 v = ((const float4*)W)[i];
        char4 o;
        o.x = (v.x > mean) ? 1 : 0;
        o.y = (v.y > mean) ? 1 : 0;
        o.z = (v.z > mean) ? 1 : 0;
        o.w = (v.w > mean) ? 1 : 0;
        ((char4*)Wq)[i] = o;
    }
}

// ---------------------------------------------------------------------------
// Kernel 3: per-row symmetric int8 quantization of x (one block per row).
// ---------------------------------------------------------------------------
__global__ void quant_x_kernel(const float* __restrict__ x, i8_t* __restrict__ xq,
                               float* __restrict__ scale, int K) {
    __shared__ float red[4];
    int row = blockIdx.x;
    int t = threadIdx.x;
    const float4* xr = (const float4*)(x + (size_t)row * K);

    float4 v[4];
    float am = 0.f;
    #pragma unroll
    for (int j = 0; j < 4; ++j) {
        v[j] = xr[t + j * 256];
        am = fmaxf(am, fmaxf(fmaxf(fabsf(v[j].x), fabsf(v[j].y)),
                             fmaxf(fabsf(v[j].z), fabsf(v[j].w))));
    }
    #pragma unroll
    for (int off = 32; off > 0; off >>= 1) am = fmaxf(am, __shfl_down(am, off, 64));
    if ((t & 63) == 0) red[t >> 6] = am;
    __syncthreads();
    float amax = fmaxf(fmaxf(red[0], red[1]), fmaxf(red[2], red[3]));
    amax = fmaxf(amax, 1e-20f);
    float s = amax * (1.0f / 127.0f);
    float inv = 127.0f / amax;
    if (t == 0) scale[row] = s;

    char4* oq = (char4*)(xq + (size_t)row * K);
    #pragma unroll
    for (int j = 0; j < 4; ++j) {
        char4 o;
        o.x = (i8_t)(int)rintf(fminf(fmaxf(v[j].x * inv, -127.f), 127.f));
        o.y = (i8_t)(int)rintf(fminf(fmaxf(v[j].y * inv, -127.f), 127.f));
        o.z = (i8_t)(int)rintf(fminf(fmaxf(v[j].z * inv, -127.f), 127.f));
        o.w = (i8_t)(int)rintf(fminf(fmaxf(v[j].w * inv, -127.f), 127.f));
        oq[t + j * 256] = o;
    }
}

// ---------------------------------------------------------------------------
// Kernel 4: quantize b (single block; n = 4096)
// ---------------------------------------------------------------------------
__global__ void quant_b_kernel(const float* __restrict__ b, float* __restrict__ bq, int n) {
    int t = threadIdx.x;
    float s = 0.f;
    for (int i = t; i < n; i += 256) s += b[i];
    #pragma unroll
    for (int off = 32; off > 0; off >>= 1) s += __shfl_down(s, off, 64);
    __shared__ float red[4];
    if ((t & 63) == 0) red[t >> 6] = s;
    __syncthreads();
    float mean = (red[0] + red[1] + red[2] + red[3]) / (float)n;
    for (int i = t; i < n; i += 256) bq[i] = (b[i] > mean) ? 1.0f : 0.0f;
}

// ---------------------------------------------------------------------------
// Kernel 5: INT8 MFMA GEMM, 256x256 tile, BK=128, 8 waves (2Mx4N), R12's
// proven 4-phase schedule (best verified: 118-126us).
// ZMODE 0: fp32 C (fallback); 1: bf16 z to workspace (halves C-write +
// rownorm-read bytes; |z_raw| <= ~7000 so bf16 adds <= ~0.011 absmax).
// ---------------------------------------------------------------------------
#define PRIO1 __builtin_amdgcn_s_setprio(1)
#define PRIO0 __builtin_amdgcn_s_setprio(0)
#define BAR() __builtin_amdgcn_s_barrier()
#define WAITV4() asm volatile("s_waitcnt vmcnt(4)" ::: "memory")
#define WAITV0() asm volatile("s_waitcnt vmcnt(0)" ::: "memory")
#define UNRL _Pragma("unroll")

__device__ __forceinline__ unsigned short f2bfu(float f) {
    __hip_bfloat16 h = __float2bfloat16(f);
    return *(unsigned short*)&h;
}

template<int ZMODE>
__global__ __launch_bounds__(512, 2) void gemm_i8_256(
        const i8_t* __restrict__ A, const i8_t* __restrict__ B,
        float* __restrict__ C, unsigned short* __restrict__ ZB,
        int M, int N, int K) {
    __shared__ int lds32[32768];       // 128 KiB: [buf][A 32K i8 | B 32K i8]
    char* ldsc = (char*)lds32;
    float* ldsf = (float*)lds32;       // epilogue bounce reuses the same LDS

    int nbn = N >> 8;
    int nwg = gridDim.x;
    int bid = blockIdx.x;
    int cpx = nwg >> 3;
    int wg = (bid & 7) * cpx + (bid >> 3);   // XCD swizzle (nwg % 8 == 0)
    int tm = wg / nbn, tn = wg % nbn;

    int t = threadIdx.x;
    int w = t >> 6, l = t & 63;
    int wr = w >> 2, wc = w & 3;             // 2 M-waves x 4 N-waves
    int wrOff = wr * 8192;                   // 64 rows * 128 B
    int wcOff = wc * 4096;                   // 32 rows * 128 B

    // read-side lane offsets (bytes), full-granule swizzle folded in
    int baseL = ((l & 15) * 128) + ((l >> 4) * 16);
    int laneA0 = baseL ^ ((l & 7) << 4);     // K bytes 0..63
    int laneA1 = laneA0 ^ 64;                // K bytes 64..127

    // stage-side source offsets (i8 elems == bytes), inverse swizzle
    int offA[2][2], offB[2][2];
    UNRL
    for (int c = 0; c < 2; ++c) {
        int o = (t + c * 512) * 16;
        int os = o ^ ((o >> 3) & 0x70);
        int lr = os >> 7;
        int col = os & 127;
        UNRL
        for (int h = 0; h < 2; ++h) {
            offA[c][h] = ((lr >> 6) * 128 + h * 64 + (lr & 63)) * K + col;
            offB[c][h] = ((lr >> 5) * 64 + h * 32 + (lr & 31)) * K + col;
        }
    }

    const i8_t* srcA = A + (size_t)tm * 256 * K;
    const i8_t* srcB = B + (size_t)tn * 256 * K;

    i32x4 acc[8][4] = {};
    i32x4 af[4][2], bf0[2][2], bf1[2][2];

#define STAGE_A(P, H, KIDX) do { \
    GLD16(srcA + (size_t)offA[0][H] + (KIDX), ldsc + (P)*65536 + (H)*16384 + w*1024); \
    GLD16(srcA + (size_t)offA[1][H] + (KIDX), ldsc + (P)*65536 + (H)*16384 + 8192 + w*1024); \
} while (0)
#define STAGE_B(P, H, KIDX) do { \
    GLD16(srcB + (size_t)offB[0][H] + (KIDX), ldsc + (P)*65536 + 32768 + (H)*16384 + w*1024); \
    GLD16(srcB + (size_t)offB[1][H] + (KIDX), ldsc + (P)*65536 + 32768 + (H)*16384 + 8192 + w*1024); \
} while (0)
#define LOAD_AF(P, H) do { UNRL for (int f = 0; f < 4; ++f) { \
    af[f][0] = *(const i32x4*)(ldsc + (P)*65536 + (H)*16384 + wrOff + f*2048 + laneA0); \
    af[f][1] = *(const i32x4*)(ldsc + (P)*65536 + (H)*16384 + wrOff + f*2048 + laneA1); \
} } while (0)
#define LOAD_BF(BF, P, H) do { UNRL for (int e = 0; e < 2; ++e) { \
    BF[e][0] = *(const i32x4*)(ldsc + (P)*65536 + 32768 + (H)*16384 + wcOff + e*2048 + laneA0); \
    BF[e][1] = *(const i32x4*)(ldsc + (P)*65536 + 32768 + (H)*16384 + wcOff + e*2048 + laneA1); \
} } while (0)
#define MFMA_Q(QM, QN, BF) do { UNRL for (int f = 0; f < 4; ++f) UNRL for (int e = 0; e < 2; ++e) { \
    acc[(QM)*4+f][(QN)*2+e] = __builtin_amdgcn_mfma_i32_16x16x64_i8(af[f][0], BF[e][0], acc[(QM)*4+f][(QN)*2+e], 0, 0, 0); \
    acc[(QM)*4+f][(QN)*2+e] = __builtin_amdgcn_mfma_i32_16x16x64_i8(af[f][1], BF[e][1], acc[(QM)*4+f][(QN)*2+e], 0, 0, 0); \
} } while (0)

#define TILE(P, PN, KTN) do { \
    LOAD_AF(P, 0); LOAD_BF(bf0, P, 0); STAGE_A(PN, 0, KTN); \
    PRIO1; MFMA_Q(0, 0, bf0); PRIO0; WAITV4(); BAR(); \
    LOAD_BF(bf1, P, 1);                STAGE_B(PN, 0, KTN); \
    PRIO1; MFMA_Q(0, 1, bf1); PRIO0; WAITV4(); BAR(); \
    LOAD_AF(P, 1);                     STAGE_B(PN, 1, KTN); \
    PRIO1; MFMA_Q(1, 1, bf1); PRIO0; WAITV4(); BAR(); \
                                       STAGE_A(PN, 1, KTN); \
    PRIO1; MFMA_Q(1, 0, bf0); PRIO0; WAITV4(); BAR(); \
} while (0)

    // prologue: stage tile 0 (K 0..127) into buf0, drain once
    STAGE_A(0, 0, 0); STAGE_B(0, 0, 0); STAGE_B(0, 1, 0); STAGE_A(0, 1, 0);
    WAITV0();
    BAR();

    for (int kt = 0; kt < K; kt += 256) {
        int kn1 = kt + 128;
        int kn2 = (kt + 256 < K) ? kt + 256 : 0;   // wrap: redundant, never read
        TILE(0, 1, kn1);
        TILE(1, 0, kn2);
    }

    WAITV0();  // drain trailing stages (incl. wrapped GLD16 into the buffers)
    BAR();     // all waves' LDS writes retired before bounce reuse

    // Coalesced epilogue via LDS bounce. Frag layout: (fm,fn,r) at
    // row = wr*128 + fm*16 + (l>>4)*4 + r, col = wc*64 + fn*16 + (l&15).
    {
        int crowW = tm * 256 + wr * 128;
        int ccolW = tn * 256 + wc * 64;
        int lq = l >> 4, lc = l & 15;
        UNRL
        for (int c = 0; c < 4; ++c) {
            UNRL
            for (int fi = 0; fi < 2; ++fi) {
                int fm = c * 2 + fi;
                UNRL
                for (int fn = 0; fn < 4; ++fn)
                    UNRL
                    for (int r = 0; r < 4; ++r)
                        ldsf[w * 2176 + (fi * 16 + lq * 4 + r) * 68 + fn * 16 + lc]
                            = (float)acc[fm][fn][r];
            }
            BAR();
            UNRL
            for (int rr = 0; rr < 8; ++rr) {
                f32x4 v = *(const f32x4*)&ldsf[w * 2176 + (rr * 4 + lq) * 68 + lc * 4];
                size_t row = (size_t)(crowW + c * 32 + rr * 4 + lq);
                if (ZMODE == 0) {
                    *(f32x4*)&C[row * N + (ccolW + lc * 4)] = v;
                } else {
                    ushort4 h;
                    h.x = f2bfu(v[0]); h.y = f2bfu(v[1]);
                    h.z = f2bfu(v[2]); h.w = f2bfu(v[3]);
                    *(ushort4*)&ZB[row * N + (ccolW + lc * 4)] = h;
                }
            }
            BAR();
        }
    }
}

// ---------------------------------------------------------------------------
// Kernel 6a (fp32-z fallback): in-place rownorm on d_out.
// ---------------------------------------------------------------------------
__device__ __forceinline__ float block_sum_256(float v, float* red) {
    #pragma unroll
    for (int off = 32; off > 0; off >>= 1) v += __shfl_down(v, off, 64);
    int t = threadIdx.x;
    __syncthreads();
    if ((t & 63) == 0) red[t >> 6] = v;
    __syncthreads();
    return red[0] + red[1] + red[2] + red[3];
}

__global__ void rownorm_kernel(float* __restrict__ z, const float* __restrict__ bq,
                               const float* __restrict__ scale, int N) {
    __shared__ float red[4];
    int row = blockIdx.x;
    float* zr = z + (size_t)row * N;
    float srow = scale[row];
    int t = threadIdx.x;

    float4 v[4];
    float s = 0.f;
    #pragma unroll
    for (int j = 0; j < 4; ++j) {
        int idx = t + j * 256;
        float4 a = ((const float4*)zr)[idx];
        float4 bb = ((const float4*)bq)[idx];
        a.x = a.x * srow + bb.x; a.y = a.y * srow + bb.y;
        a.z = a.z * srow + bb.z; a.w = a.w * srow + bb.w;
        v[j] = a;
        s += (a.x + a.y) + (a.z + a.w);
    }
    float total = block_sum_256(s, red);
    float mean = total * (1.0f / 4096.0f);

    float q = 0.f;
    #pragma unroll
    for (int j = 0; j < 4; ++j) {
        float dx = v[j].x - mean, dy = v[j].y - mean, dz = v[j].z - mean, dw = v[j].w - mean;
        q += (dx * dx + dy * dy) + (dz * dz + dw * dw);
    }
    float qtot = block_sum_256(q, red);
    float var = qtot * (1.0f / 4095.0f);
    float inv = 1.0f / (sqrtf(var) + 1e-8f);

    #pragma unroll
    for (int j = 0; j < 4; ++j) {
        int idx = t + j * 256;
        float4 o;
        o.x = (v[j].x - mean) * inv;
        o.y = (v[j].y - mean) * inv;
        o.z = (v[j].z - mean) * inv;
        o.w = (v[j].w - mean) * inv;
        ((float4*)zr)[idx] = o;
    }
}

// ---------------------------------------------------------------------------
// Kernel 6b (bf16-z path): read bf16 z from ws, write fp32 out (plain stores;
// R20 showed nontemporal stores cost ~15us here -- reverted).
// ---------------------------------------------------------------------------
__global__ void rownorm_bf16_kernel(const unsigned short* __restrict__ zb,
                                    float* __restrict__ out,
                                    const float* __restrict__ bq,
                                    const float* __restrict__ scale, int N) {
    __shared__ float red[4];
    int row = blockIdx.x;
    const unsigned short* zr = zb + (size_t)row * N;
    float* orow = out + (size_t)row * N;
    float srow = scale[row];
    int t = threadIdx.x;

    float v[16];
    float s = 0.f;
    #pragma unroll
    for (int j = 0; j < 2; ++j) {
        int idx8 = t + j * 256;                 // ushort8 index
        u16x8 u = ((const u16x8*)zr)[idx8];
        float4 b0 = ((const float4*)bq)[idx8 * 2];
        float4 b1 = ((const float4*)bq)[idx8 * 2 + 1];
        #pragma unroll
        for (int e = 0; e < 8; ++e) {
            unsigned int bits = ((unsigned int)u[e]) << 16;
            float f = *(float*)&bits;
            float bb = (e < 4) ? ((const float*)&b0)[e] : ((const float*)&b1)[e - 4];
            float a = f * srow + bb;
            v[j * 8 + e] = a;
            s += a;
        }
    }
    float total = block_sum_256(s, red);
    float mean = total * (1.0f / 4096.0f);

    float q = 0.f;
    #pragma unroll
    for (int i = 0; i < 16; ++i) {
        float d = v[i] - mean;
        q += d * d;
    }
    float qtot = block_sum_256(q, red);
    float var = qtot * (1.0f / 4095.0f);
    float inv = 1.0f / (sqrtf(var) + 1e-8f);

    #pragma unroll
    for (int j = 0; j < 2; ++j) {
        int idx8 = t + j * 256;
        #pragma unroll
        for (int p = 0; p < 2; ++p) {
            float4 o;
            o.x = (v[j * 8 + p * 4 + 0] - mean) * inv;
            o.y = (v[j * 8 + p * 4 + 1] - mean) * inv;
            o.z = (v[j * 8 + p * 4 + 2] - mean) * inv;
            o.w = (v[j * 8 + p * 4 + 3] - mean) * inv;
            ((float4*)orow)[idx8 * 2 + p] = o;
        }
    }
}

// ---------------------------------------------------------------------------
extern "C" void kernel_launch(void* const* d_in, const int* in_sizes, int n_in,
                              void* d_out, int out_size, void* d_ws, size_t ws_size,
                              hipStream_t stream) {
    const float* x = (const float*)d_in[0];
    const float* W = (const float*)d_in[1];
    const float* b = (const float*)d_in[2];
    float* out = (float*)d_out;

    const int N = in_sizes[2];            // 4096 (OUT)
    const int K = in_sizes[1] / N;        // 4096 (IN)
    const int M = in_sizes[0] / K;        // 8192

    // workspace layout
    char* ws = (char*)d_ws;
    size_t off_xq = 0;
    size_t off_wq = off_xq + (size_t)M * K;                 // i8
    size_t off_scales = off_wq + (size_t)N * K;             // i8
    size_t off_bq = off_scales + (size_t)M * 4;
    size_t off_sumw = off_bq + (size_t)N * 4;
    size_t off_zb = (off_sumw + 8 + 15) & ~(size_t)15;      // 16-aligned
    size_t need_bf16z = off_zb + (size_t)M * N * 2;

    i8_t* xq = (i8_t*)(ws + off_xq);
    i8_t* wq = (i8_t*)(ws + off_wq);
    float* scales = (float*)(ws + off_scales);
    float* bq = (float*)(ws + off_bq);
    double* sumw = (double*)(ws + off_sumw);
    unsigned short* zb = (unsigned short*)(ws + off_zb);

    bool use_bf16z = (ws_size >= need_bf16z);

    hipMemsetAsync(sumw, 0, sizeof(double), stream);
    sum_w_kernel<<<1024, 256, 0, stream>>>(W, sumw, N * K / 4);
    quant_w_kernel<<<2048, 256, 0, stream>>>(W, wq, sumw, 1.0f / (float)((size_t)N * K), N * K / 4);
    quant_x_kernel<<<M, 256, 0, stream>>>(x, xq, scales, K);
    quant_b_kernel<<<1, 256, 0, stream>>>(b, bq, N);

    int grid = (M / 256) * (N / 256);
    if (use_bf16z) {
        gemm_i8_256<1><<<grid, 512, 0, stream>>>(xq, wq, out, zb, M, N, K);
        rownorm_bf16_kernel<<<M, 256, 0, stream>>>(zb, out, bq, scales, N);
    } else {
        gemm_i8_256<0><<<grid, 512, 0, stream>>>(xq, wq, out, zb, M, N, K);
        rownorm_kernel<<<M, 256, 0, stream>>>(out, bq, scales, N);
    }
}